// Round 9
// baseline (688.778 us; speedup 1.0000x reference)
//
#include <hip/hip_runtime.h>
#include <hip/hip_bf16.h>
#include <stdint.h>

// cheb_conv_with_Att_static: out[b,t,v,c] = relu( sum_{k,f} theta[k,f,c] *
//     sum_u cheb[k,u,v]*Att[b,u,v]*x[b,t,u,f] )
// B=8 T=12 V=2048 F=16 K=3 C=64
#define B_  8
#define T_  12
#define V_  2048
#define F_  16
#define K_  3
#define C_  64
#define N_  192   // T*F

typedef _Float16 f16;
typedef _Float16 half2v __attribute__((ext_vector_type(2)));
typedef _Float16 half4v __attribute__((ext_vector_type(4)));
typedef _Float16 half8v __attribute__((ext_vector_type(8)));
typedef float    f32x4  __attribute__((ext_vector_type(4)));
typedef float    f32x16 __attribute__((ext_vector_type(16)));
typedef unsigned int u32;

// ---------------------------------------------------------------------------
// Kernel 1a: XT[b][n=t*16+f][u] = (f16) x[b][t][u][f]   (u becomes contiguous)
// ---------------------------------------------------------------------------
__global__ __launch_bounds__(256) void prep_xt(const float* __restrict__ x,
                                               f16* __restrict__ XT) {
  int bid = blockIdx.x;
  int bt = bid >> 2, uc = bid & 3;
  int b = bt / T_, t = bt % T_;
  __shared__ float tile[64][17];
  int r  = threadIdx.x >> 2, fq = threadIdx.x & 3;   // load mapping
  int f  = threadIdx.x >> 4, uq = threadIdx.x & 15;  // store mapping
  for (int u0 = uc * 512; u0 < uc * 512 + 512; u0 += 64) {
    f32x4 v = *(const f32x4*)(x + ((size_t)(b * T_ + t) * V_ + u0 + r) * F_ + fq * 4);
    tile[r][fq * 4 + 0] = v[0];
    tile[r][fq * 4 + 1] = v[1];
    tile[r][fq * 4 + 2] = v[2];
    tile[r][fq * 4 + 3] = v[3];
    __syncthreads();
    half4v h;
    h[0] = (f16)tile[uq * 4 + 0][f];
    h[1] = (f16)tile[uq * 4 + 1][f];
    h[2] = (f16)tile[uq * 4 + 2][f];
    h[3] = (f16)tile[uq * 4 + 3][f];
    *(half4v*)(XT + (size_t)(b * N_ + t * F_ + f) * V_ + u0 + uq * 4) = h;
    __syncthreads();
  }
}

// ---------------------------------------------------------------------------
// Kernel 1b: chebT = f16 transpose of cheb, blocked for 16x16x32 A-frags:
//   elem(k,v,u) at (((k*128 + (v>>4))*256 + (u>>3))*16 + (v&15))*8 + (u&7)
// A wave-fragment (16 v-rows x 32 u; lane l: v=l&15, u=(l>>4)*8..+8) is
// 1 KB CONTIGUOUS per wave -> one coalesced 16B/lane load.
// ---------------------------------------------------------------------------
__global__ __launch_bounds__(256) void prep_chebT(const float* __restrict__ c,
                                                  f16* __restrict__ cT) {
  int bid = blockIdx.x;
  int vt = bid & 31, ut = (bid >> 5) & 31, k = bid >> 10;
  int u0 = ut * 64, v0 = vt * 64;
  __shared__ float tile[64][68];
  int tid = threadIdx.x;
  int lr = tid >> 4, lc = (tid & 15) * 4;
  const float* src = c + ((size_t)k * V_ + u0) * V_ + v0;
#pragma unroll
  for (int i = 0; i < 4; ++i) {
    f32x4 v = *(const f32x4*)(src + (size_t)(lr + 16 * i) * V_ + lc);
    tile[lr + 16 * i][lc + 0] = v[0];
    tile[lr + 16 * i][lc + 1] = v[1];
    tile[lr + 16 * i][lc + 2] = v[2];
    tile[lr + 16 * i][lc + 3] = v[3];
  }
  __syncthreads();
  int vl = tid & 63, uc0 = tid >> 6;
#pragma unroll
  for (int i = 0; i < 2; ++i) {
    int uc = uc0 + 4 * i;                 // u-chunk 0..7
    half8v h;
#pragma unroll
    for (int j = 0; j < 8; ++j) h[j] = (f16)tile[uc * 8 + j][vl];
    int vb16 = vt * 4 + (vl >> 4);        // v>>4
    int vi   = vl & 15;
    int ub8  = ut * 8 + uc;               // u>>3
    size_t off = ((((size_t)k * 128 + vb16) * 256 + ub8) * 16 + vi) * 8;
    *(half8v*)(cT + off) = h;
  }
}

// ---------------------------------------------------------------------------
// Kernel 2 (round-9): 8-WAVE blocks.  Per (b,vt,uh), all 3 k:
//   rhs[b][t][v][uh*48+k*16+f] = sum_{u in half} (cheb[k,u,v]*Att[b,u,v]) * XT
// BM=64, BN=192, BK=64; 8 waves (2v x 4n), wave tile 32v x 48n, 16x16x32 MFMA.
// acc = 3k x 2vi x 3ni x f32x4 = 72 AGPR/wave.  LDS 64KB (B 2x24K, att 2x8K)
// -> 2 blocks/CU = 16 waves/CU = 4 waves/SIMD (regs: ~250/wave, 4x250 < 2048).
// Two INDEPENDENT blocks per CU desynchronize barriers -> stalls overlap.
// cheb frags reg-prefetched dbuf (cfA/cfB) from 16-blocked chebT (L2-pinned:
// vt%8 == bid%8).  att LDS key ((v+(v>>3))&7)<<4 both sides (write stride-4
// all-8 spread AND read 16-consecutive all-8 spread).  B glds linear dest +
// pre-swizzled src, read key (n&7)<<4.
// ---------------------------------------------------------------------------
#define MFMA16(a, b, c) __builtin_amdgcn_mfma_f32_16x16x32_f16(a, b, c, 0, 0, 0)

#define KS_STEP(ks, AC, BC, CF)                                                 \
  {                                                                             \
    const int ub = (ks) * 64 + lg * 16;                                         \
    half8v af0 = *(const half8v*)((AC) + aoff0 + (ub ^ ak0));                   \
    half8v af1 = *(const half8v*)((AC) + aoff1 + (ub ^ ak1));                   \
    half8v b0 = *(const half8v*)((BC) + n0 * 128 + (ub ^ bk0));                 \
    half8v b1 = *(const half8v*)((BC) + n1 * 128 + (ub ^ bk1));                 \
    half8v b2 = *(const half8v*)((BC) + n2 * 128 + (ub ^ bk2));                 \
    half8v a00 = CF[0 * 4 + 0 * 2 + (ks)] * af0;                                \
    half8v a01 = CF[0 * 4 + 1 * 2 + (ks)] * af1;                                \
    half8v a10 = CF[1 * 4 + 0 * 2 + (ks)] * af0;                                \
    half8v a11 = CF[1 * 4 + 1 * 2 + (ks)] * af1;                                \
    half8v a20 = CF[2 * 4 + 0 * 2 + (ks)] * af0;                                \
    half8v a21 = CF[2 * 4 + 1 * 2 + (ks)] * af1;                                \
    __builtin_amdgcn_s_setprio(1);                                              \
    acc[0][0][0] = MFMA16(a00, b0, acc[0][0][0]);                               \
    acc[0][0][1] = MFMA16(a00, b1, acc[0][0][1]);                               \
    acc[0][0][2] = MFMA16(a00, b2, acc[0][0][2]);                               \
    acc[0][1][0] = MFMA16(a01, b0, acc[0][1][0]);                               \
    acc[0][1][1] = MFMA16(a01, b1, acc[0][1][1]);                               \
    acc[0][1][2] = MFMA16(a01, b2, acc[0][1][2]);                               \
    acc[1][0][0] = MFMA16(a10, b0, acc[1][0][0]);                               \
    acc[1][0][1] = MFMA16(a10, b1, acc[1][0][1]);                               \
    acc[1][0][2] = MFMA16(a10, b2, acc[1][0][2]);                               \
    acc[1][1][0] = MFMA16(a11, b0, acc[1][1][0]);                               \
    acc[1][1][1] = MFMA16(a11, b1, acc[1][1][1]);                               \
    acc[1][1][2] = MFMA16(a11, b2, acc[1][1][2]);                               \
    acc[2][0][0] = MFMA16(a20, b0, acc[2][0][0]);                               \
    acc[2][0][1] = MFMA16(a20, b1, acc[2][0][1]);                               \
    acc[2][0][2] = MFMA16(a20, b2, acc[2][0][2]);                               \
    acc[2][1][0] = MFMA16(a21, b0, acc[2][1][0]);                               \
    acc[2][1][1] = MFMA16(a21, b1, acc[2][1][1]);                               \
    acc[2][1][2] = MFMA16(a21, b2, acc[2][1][2]);                               \
    __builtin_amdgcn_s_setprio(0);                                              \
  }

template<int UH>
__global__ __launch_bounds__(512, 4) void gemm5(const float* __restrict__ Att,
                                                const f16* __restrict__ chebT,
                                                const f16* __restrict__ XT,
                                                f16* __restrict__ rhs) {
  constexpr int NSTEP = (V_ / UH) / 64;   // 16 (UH=2) / 32 (UH=1)
  const int bid = blockIdx.x;
  const int vt = (bid & 7) | (((bid >> 3) & 3) << 3);   // 0..31, vt%8 == bid%8
  const int rr = bid >> 5;                              // 0..8*UH-1
  const int uh = rr % UH;
  const int b  = rr / UH;
  const int vbase = vt * 64;
  const size_t ubase = (size_t)uh * (V_ / UH);

  __shared__ char smem[65536];            // B0 24K | B1 24K | A0 8K | A1 8K
  char* Bb0 = smem;
  char* Bb1 = smem + 24576;
  char* Ab0 = smem + 49152;
  char* Ab1 = smem + 57344;

  const int tid = threadIdx.x;
  const int wave = tid >> 6, lane = tid & 63;
  const int wv = wave >> 2, wn = wave & 3;   // 2v x 4n wave grid
  const int l15 = lane & 15, lg = lane >> 4; // lg 0..3 (k-chunk)

  // A (att) fragment addressing: two 16-row v-frags per wave
  const int va0 = wv * 32 + l15, va1 = va0 + 16;
  const int ak0 = ((va0 + (va0 >> 3)) & 7) << 4;
  const int ak1 = ((va1 + (va1 >> 3)) & 7) << 4;
  const int aoff0 = va0 * 128, aoff1 = va1 * 128;

  // B fragments: 3 n-subtiles per wave
  const int n0 = wn * 48 + l15, n1 = n0 + 16, n2 = n0 + 32;
  const int bk0 = (n0 & 7) << 4, bk1 = (n1 & 7) << 4, bk2 = (n2 & 7) << 4;

  // cheb base pointers (k x vi), 16-blocked layout
  const f16* chb[3][2];
#pragma unroll
  for (int k = 0; k < 3; ++k)
#pragma unroll
    for (int vi = 0; vi < 2; ++vi) {
      int vb16 = vt * 4 + wv * 2 + vi;
      chb[k][vi] = chebT + (((size_t)k * 128 + vb16) * 256 + (ubase >> 3)) * 128
                 + lg * 128 + l15 * 8;
    }

  // att staging: thread covers 4v x 2u
  const int vsub = (tid & 15) * 4;
  const int up   = tid >> 4;               // 0..31 -> u pair {2up, 2up+1}
  const float* attb = Att + (size_t)b * V_ * V_ + (ubase + 2 * up) * V_ + vbase + vsub;

  // B glds: 24 slots x 1KB, 3 per wave
  const f16* xtb = XT + (size_t)b * N_ * V_ + ubase;

  f32x4 acc[3][2][3];
#pragma unroll
  for (int k = 0; k < 3; ++k)
#pragma unroll
    for (int vi = 0; vi < 2; ++vi)
#pragma unroll
      for (int ni = 0; ni < 3; ++ni) acc[k][vi][ni] = 0;

  f32x4 p0, p1;

  auto stageB = [&](int t, char* Bb) {
#pragma unroll
    for (int e = 0; e < 3; ++e) {
      int slot = wave * 3 + e;
      int n = slot * 8 + (lane >> 3);
      int cc = (lane & 7) ^ (n & 7);
      const f16* src = xtb + (size_t)n * V_ + t * 64 + cc * 8;
      __builtin_amdgcn_global_load_lds((const __attribute__((address_space(1))) u32*)src,
                                       (__attribute__((address_space(3))) u32*)(Bb + slot * 1024),
                                       16, 0, 0);
    }
  };
  auto issueAtt = [&](int t) {
    p0 = *(const f32x4*)(attb + (size_t)(t * 64) * V_);
    p1 = *(const f32x4*)(attb + (size_t)(t * 64 + 1) * V_);
  };
  auto writeAtt = [&](char* Aw) {
#pragma unroll
    for (int j = 0; j < 4; ++j) {
      int v2 = vsub + j;
      half2v h;
      h[0] = (f16)p0[j]; h[1] = (f16)p1[j];
      *(half2v*)(Aw + v2 * 128 + ((4 * up) ^ (((v2 + (v2 >> 3)) & 7) << 4))) = h;
    }
  };
  auto loadCheb = [&](int t, half8v cf[12]) {
#pragma unroll
    for (int k = 0; k < 3; ++k)
#pragma unroll
      for (int vi = 0; vi < 2; ++vi)
#pragma unroll
        for (int ks = 0; ks < 2; ++ks)
          cf[k * 4 + vi * 2 + ks] =
              *(const half8v*)(chb[k][vi] + (size_t)(t * 8 + ks * 4) * 128);
  };

  half8v cfA[12], cfB[12];

  // ---- prologue: stage step 0 ----
  issueAtt(0);
  stageB(0, Bb0);
  loadCheb(0, cfA);
  writeAtt(Ab0);
  __syncthreads();

#pragma unroll 1
  for (int t0 = 0; t0 < NSTEP; t0 += 2) {
    {
      // even phase: compute t0 from {Ab0,Bb0,cfA}; prefetch t0+1
      issueAtt(t0 + 1);
      stageB(t0 + 1, Bb1);
      loadCheb(t0 + 1, cfB);
      KS_STEP(0, Ab0, Bb0, cfA)
      KS_STEP(1, Ab0, Bb0, cfA)
      writeAtt(Ab1);
      __syncthreads();
    }
    {
      // odd phase: compute t0+1 from {Ab1,Bb1,cfB}; prefetch t0+2
      const bool p2 = (t0 + 2) < NSTEP;
      if (p2) {
        issueAtt(t0 + 2);
        stageB(t0 + 2, Bb0);
        loadCheb(t0 + 2, cfA);
      }
      KS_STEP(0, Ab1, Bb1, cfB)
      KS_STEP(1, Ab1, Bb1, cfB)
      if (p2) writeAtt(Ab0);
      __syncthreads();
    }
  }

  // ---- epilogue: scatter acc -> rhs[b][t][v][uh*48 + k*16 + f] (f16) ----
#pragma unroll
  for (int ni = 0; ni < 3; ++ni) {
    int n = wn * 48 + ni * 16 + l15;
    int tt = n >> 4, fi = n & 15;
#pragma unroll
    for (int k = 0; k < 3; ++k)
#pragma unroll
      for (int vi = 0; vi < 2; ++vi)
#pragma unroll
        for (int r = 0; r < 4; ++r) {
          int v = vbase + wv * 32 + vi * 16 + lg * 4 + r;
          rhs[((size_t)(b * T_ + tt) * V_ + v) * (48 * UH) + uh * 48 + k * 16 + fi] =
              (f16)acc[k][vi][ni][r];
        }
  }
}

// ---------------------------------------------------------------------------
// Kernel 3: out[row, c] = relu( sum_{s} rhs[row][s*16+..] * theta[(s%3)*16+..][c] )
// ---------------------------------------------------------------------------
template<int UH>
__global__ __launch_bounds__(256) void epi(const f16* __restrict__ rhs,
                                           const float* __restrict__ theta,
                                           float* __restrict__ out) {
  int wave = threadIdx.x >> 6, lane = threadIdx.x & 63;
  int row0 = blockIdx.x * 128 + wave * 32;
  int cl = lane & 31, kh = (lane >> 5) * 8;

  half8v bf[2][3];
#pragma unroll
  for (int nf = 0; nf < 2; ++nf)
#pragma unroll
    for (int ks = 0; ks < 3; ++ks) {
      half8v hb;
#pragma unroll
      for (int j = 0; j < 8; ++j)
        hb[j] = (f16)theta[(size_t)(ks * 16 + kh + j) * C_ + nf * 32 + cl];
      bf[nf][ks] = hb;
    }

  f32x16 acc0 = 0, acc1 = 0;
#pragma unroll
  for (int s = 0; s < 3 * UH; ++s) {
    half8v a = *(const half8v*)(rhs + (size_t)(row0 + cl) * (48 * UH) + s * 16 + kh);
    acc0 = __builtin_amdgcn_mfma_f32_32x32x16_f16(a, bf[0][s % 3], acc0, 0, 0, 0);
    acc1 = __builtin_amdgcn_mfma_f32_32x32x16_f16(a, bf[1][s % 3], acc1, 0, 0, 0);
  }
#pragma unroll
  for (int r = 0; r < 16; ++r) {
    int row = row0 + (r & 3) + 8 * (r >> 2) + 4 * (lane >> 5);
    out[(size_t)row * C_ + cl]      = fmaxf(acc0[r], 0.f);
    out[(size_t)row * C_ + 32 + cl] = fmaxf(acc1[r], 0.f);
  }
}

// ---------------------------------------------------------------------------
extern "C" void kernel_launch(void* const* d_in, const int* in_sizes, int n_in,
                              void* d_out, int out_size, void* d_ws, size_t ws_size,
                              hipStream_t stream) {
  const float* x     = (const float*)d_in[0];   // (8,12,2048,16)
  const float* Att   = (const float*)d_in[1];   // (8,2048,2048)
  const float* cheb  = (const float*)d_in[2];   // (3,2048,2048)
  const float* theta = (const float*)d_in[3];   // (3,16,64)
  float* out = (float*)d_out;                   // (8,12,2048,64) fp32

  const size_t xtB   = (size_t)B_ * N_ * V_ * sizeof(f16);        // 6.29 MB
  const size_t rhs2B = (size_t)B_ * T_ * V_ * 96 * sizeof(f16);   // 37.7 MB
  const size_t rhs1B = rhs2B / 2;                                 // 18.9 MB
  const size_t chB   = (size_t)K_ * V_ * V_ * sizeof(f16);        // 25.2 MB

  f16* XT = (f16*)d_ws;
  prep_xt<<<B_ * T_ * 4, 256, 0, stream>>>(x, XT);

  if (ws_size >= xtB + rhs2B + chB) {
    f16* rhs = (f16*)((char*)d_ws + xtB);
    f16* cT  = (f16*)((char*)d_ws + xtB + rhs2B);
    prep_chebT<<<K_ * 32 * 32, 256, 0, stream>>>(cheb, cT);
    gemm5<2><<<B_ * 32 * 2, 512, 0, stream>>>(Att, cT, XT, rhs);
    epi<2><<<(B_ * T_ * V_) / 128, 256, 0, stream>>>(rhs, theta, out);
  } else {
    f16* rhs = (f16*)((char*)d_ws + xtB);
    f16* cT  = (f16*)((char*)d_ws + xtB + rhs1B);
    prep_chebT<<<K_ * 32 * 32, 256, 0, stream>>>(cheb, cT);
    gemm5<1><<<B_ * 32, 512, 0, stream>>>(Att, cT, XT, rhs);
    epi<1><<<(B_ * T_ * V_) / 128, 256, 0, stream>>>(rhs, theta, out);
  }
}

// Round 10
// 125.273 us; speedup vs baseline: 5.4982x; 5.4982x over previous
//
#include <hip/hip_runtime.h>
#include <hip/hip_bf16.h>
#include <stdint.h>

// cheb_conv_with_Att_static: out[b,t,v,c] = relu( sum_{k,f} theta[k,f,c] *
//     sum_u cheb[k,u,v]*Att[b,u,v]*x[b,t,u,f] )
// B=8 T=12 V=2048 F=16 K=3 C=64
#define B_  8
#define T_  12
#define V_  2048
#define F_  16
#define K_  3
#define C_  64
#define N_  192   // T*F

typedef _Float16 f16;
typedef _Float16 half2v __attribute__((ext_vector_type(2)));
typedef _Float16 half4v __attribute__((ext_vector_type(4)));
typedef _Float16 half8v __attribute__((ext_vector_type(8)));
typedef float    f32x4  __attribute__((ext_vector_type(4)));
typedef float    f32x16 __attribute__((ext_vector_type(16)));
typedef unsigned int u32;

// ---------------------------------------------------------------------------
// Kernel 1a: XT[b][n=t*16+f][u] = (f16) x[b][t][u][f]   (u becomes contiguous)
// ---------------------------------------------------------------------------
__global__ __launch_bounds__(256) void prep_xt(const float* __restrict__ x,
                                               f16* __restrict__ XT) {
  int bid = blockIdx.x;
  int bt = bid >> 2, uc = bid & 3;
  int b = bt / T_, t = bt % T_;
  __shared__ float tile[64][17];
  int r  = threadIdx.x >> 2, fq = threadIdx.x & 3;   // load mapping
  int f  = threadIdx.x >> 4, uq = threadIdx.x & 15;  // store mapping
  for (int u0 = uc * 512; u0 < uc * 512 + 512; u0 += 64) {
    f32x4 v = *(const f32x4*)(x + ((size_t)(b * T_ + t) * V_ + u0 + r) * F_ + fq * 4);
    tile[r][fq * 4 + 0] = v[0];
    tile[r][fq * 4 + 1] = v[1];
    tile[r][fq * 4 + 2] = v[2];
    tile[r][fq * 4 + 3] = v[3];
    __syncthreads();
    half4v h;
    h[0] = (f16)tile[uq * 4 + 0][f];
    h[1] = (f16)tile[uq * 4 + 1][f];
    h[2] = (f16)tile[uq * 4 + 2][f];
    h[3] = (f16)tile[uq * 4 + 3][f];
    *(half4v*)(XT + (size_t)(b * N_ + t * F_ + f) * V_ + u0 + uq * 4) = h;
    __syncthreads();
  }
}

// ---------------------------------------------------------------------------
// Kernel 1b: chebT = f16 transpose of cheb, blocked for 16x16x32 A-frags:
//   elem(k,v,u) at (((k*128 + (v>>4))*256 + (u>>3))*16 + (v&15))*8 + (u&7)
// (validated in round 7)
// ---------------------------------------------------------------------------
__global__ __launch_bounds__(256) void prep_chebT(const float* __restrict__ c,
                                                  f16* __restrict__ cT) {
  int bid = blockIdx.x;
  int vt = bid & 31, ut = (bid >> 5) & 31, k = bid >> 10;
  int u0 = ut * 64, v0 = vt * 64;
  __shared__ float tile[64][68];
  int tid = threadIdx.x;
  int lr = tid >> 4, lc = (tid & 15) * 4;
  const float* src = c + ((size_t)k * V_ + u0) * V_ + v0;
#pragma unroll
  for (int i = 0; i < 4; ++i) {
    f32x4 v = *(const f32x4*)(src + (size_t)(lr + 16 * i) * V_ + lc);
    tile[lr + 16 * i][lc + 0] = v[0];
    tile[lr + 16 * i][lc + 1] = v[1];
    tile[lr + 16 * i][lc + 2] = v[2];
    tile[lr + 16 * i][lc + 3] = v[3];
  }
  __syncthreads();
  int vl = tid & 63, uc0 = tid >> 6;
#pragma unroll
  for (int i = 0; i < 2; ++i) {
    int uc = uc0 + 4 * i;                 // u-chunk 0..7
    half8v h;
#pragma unroll
    for (int j = 0; j < 8; ++j) h[j] = (f16)tile[uc * 8 + j][vl];
    int vb16 = vt * 4 + (vl >> 4);        // v>>4
    int vi   = vl & 15;
    int ub8  = ut * 8 + uc;               // u>>3
    size_t off = ((((size_t)k * 128 + vb16) * 256 + ub8) * 16 + vi) * 8;
    *(half8v*)(cT + off) = h;
  }
}

// ---------------------------------------------------------------------------
// Kernel 2 (round-10): REGISTER-BUDGETED for 2 waves/SIMD (pool = 512/SIMD).
// Per (b,vt): all 3 k, full K=2048:
//   rhs[b][t][v][k*16+f] = sum_u (cheb[k,u,v]*Att[b,u,v]) * XT[b,n,u]
// BM=32, BN=192, BK=64; 4 waves (1v x 4n), wave tile 32v x 48n, 16x16x32 MFMA.
// acc = 3k x 2vi x 3ni x f32x4 = 72 AGPR; total ~200 <= 256 (LB(256,2)).
// LDS 56KB (B 2x24K + att 2x4K) -> 2 INDEPENDENT blocks/CU (112KB), grid=512
// = all co-resident; desynchronized barriers overlap each other's stalls.
// cheb frags loaded at use from blocked chebT (L2, XCD-pinned vt%8==bid%8);
// att read once (HBM floor); B via glds dbuf (validated structure).
// ---------------------------------------------------------------------------
#define MFMA16(a, b, c) __builtin_amdgcn_mfma_f32_16x16x32_f16(a, b, c, 0, 0, 0)

#define KS_STEP(ks, AC, BC, tt)                                                 \
  {                                                                             \
    const int ub = (ks) * 64 + lg * 16;                                         \
    half8v af0 = *(const half8v*)((AC) + l15 * 128 + (ub ^ ak0));               \
    half8v af1 = *(const half8v*)((AC) + (l15 + 16) * 128 + (ub ^ ak1));        \
    half8v b0 = *(const half8v*)((BC) + n0 * 128 + (ub ^ bk0));                 \
    half8v b1 = *(const half8v*)((BC) + n1 * 128 + (ub ^ bk1));                 \
    half8v b2 = *(const half8v*)((BC) + n2 * 128 + (ub ^ bk2));                 \
    const size_t co = (size_t)((tt) * 8 + (ks) * 4) * 128;                      \
    half8v c00 = *(const half8v*)(chb00 + co);                                  \
    half8v c01 = *(const half8v*)(chb01 + co);                                  \
    half8v c10 = *(const half8v*)(chb10 + co);                                  \
    half8v c11 = *(const half8v*)(chb11 + co);                                  \
    half8v c20 = *(const half8v*)(chb20 + co);                                  \
    half8v c21 = *(const half8v*)(chb21 + co);                                  \
    half8v a00 = c00 * af0, a01 = c01 * af1;                                    \
    half8v a10 = c10 * af0, a11 = c11 * af1;                                    \
    half8v a20 = c20 * af0, a21 = c21 * af1;                                    \
    __builtin_amdgcn_s_setprio(1);                                              \
    acc[0][0][0] = MFMA16(a00, b0, acc[0][0][0]);                               \
    acc[0][0][1] = MFMA16(a00, b1, acc[0][0][1]);                               \
    acc[0][0][2] = MFMA16(a00, b2, acc[0][0][2]);                               \
    acc[0][1][0] = MFMA16(a01, b0, acc[0][1][0]);                               \
    acc[0][1][1] = MFMA16(a01, b1, acc[0][1][1]);                               \
    acc[0][1][2] = MFMA16(a01, b2, acc[0][1][2]);                               \
    acc[1][0][0] = MFMA16(a10, b0, acc[1][0][0]);                               \
    acc[1][0][1] = MFMA16(a10, b1, acc[1][0][1]);                               \
    acc[1][0][2] = MFMA16(a10, b2, acc[1][0][2]);                               \
    acc[1][1][0] = MFMA16(a11, b0, acc[1][1][0]);                               \
    acc[1][1][1] = MFMA16(a11, b1, acc[1][1][1]);                               \
    acc[1][1][2] = MFMA16(a11, b2, acc[1][1][2]);                               \
    acc[2][0][0] = MFMA16(a20, b0, acc[2][0][0]);                               \
    acc[2][0][1] = MFMA16(a20, b1, acc[2][0][1]);                               \
    acc[2][0][2] = MFMA16(a20, b2, acc[2][0][2]);                               \
    acc[2][1][0] = MFMA16(a21, b0, acc[2][1][0]);                               \
    acc[2][1][1] = MFMA16(a21, b1, acc[2][1][1]);                               \
    acc[2][1][2] = MFMA16(a21, b2, acc[2][1][2]);                               \
    __builtin_amdgcn_s_setprio(0);                                              \
  }

__global__ __launch_bounds__(256, 2) void gemm6(const float* __restrict__ Att,
                                                const f16* __restrict__ chebT,
                                                const f16* __restrict__ XT,
                                                f16* __restrict__ rhs) {
  constexpr int NSTEP = V_ / 64;          // 32
  const int bid = blockIdx.x;
  const int vt = bid & 63;                // vt%8 == bid%8 -> XCD-pinned cheb
  const int b  = bid >> 6;
  const int vbase = vt * 32;

  __shared__ char smem[57344];            // B0 24K | B1 24K | A0 4K | A1 4K
  char* Bb0 = smem;
  char* Bb1 = smem + 24576;
  char* Ab0 = smem + 49152;
  char* Ab1 = smem + 53248;

  const int tid = threadIdx.x;
  const int wave = tid >> 6, lane = tid & 63;
  const int wn = wave;                    // 1v x 4n wave grid
  const int l15 = lane & 15, lg = lane >> 4;

  // A (att) swizzle keys for the two 16-row v-frags (rows l15, l15+16)
  const int va0 = l15, va1 = l15 + 16;
  const int ak0 = ((va0 + (va0 >> 3)) & 7) << 4;
  const int ak1 = ((va1 + (va1 >> 3)) & 7) << 4;

  // B fragments: 3 n-subtiles per wave
  const int n0 = wn * 48 + l15, n1 = n0 + 16, n2 = n0 + 32;
  const int bk0 = (n0 & 7) << 4, bk1 = (n1 & 7) << 4, bk2 = (n2 & 7) << 4;

  // cheb lane base pointers (k x vi), 16-blocked layout (validated r7)
  const f16* chb00 = chebT + (((size_t)0 * 128 + (vt * 2 + 0)) * 256) * 128 + lg * 128 + l15 * 8;
  const f16* chb01 = chebT + (((size_t)0 * 128 + (vt * 2 + 1)) * 256) * 128 + lg * 128 + l15 * 8;
  const f16* chb10 = chb00 + (size_t)V_ * V_;
  const f16* chb11 = chb01 + (size_t)V_ * V_;
  const f16* chb20 = chb10 + (size_t)V_ * V_;
  const f16* chb21 = chb11 + (size_t)V_ * V_;

  // att staging: thread covers 4v x 2u  (vsub = (tid&7)*4, up = tid>>3)
  const int vsub = (tid & 7) * 4;
  const int up   = tid >> 3;              // 0..31 -> u pair {2up, 2up+1}
  const float* attb = Att + (size_t)b * V_ * V_ + (size_t)(2 * up) * V_ + vbase + vsub;

  // B glds: 24 slots x 1KB, 6 per wave (validated r6/r8)
  const f16* xtb = XT + (size_t)b * N_ * V_;

  f32x4 acc[3][2][3];
#pragma unroll
  for (int k = 0; k < 3; ++k)
#pragma unroll
    for (int vi = 0; vi < 2; ++vi)
#pragma unroll
      for (int ni = 0; ni < 3; ++ni) acc[k][vi][ni] = 0;

  f32x4 p0, p1;

  auto stageB = [&](int t, char* Bb) {
#pragma unroll
    for (int e = 0; e < 6; ++e) {
      int slot = wave * 6 + e;
      int n = slot * 8 + (lane >> 3);
      int cc = (lane & 7) ^ (n & 7);
      const f16* src = xtb + (size_t)n * V_ + t * 64 + cc * 8;
      __builtin_amdgcn_global_load_lds((const __attribute__((address_space(1))) u32*)src,
                                       (__attribute__((address_space(3))) u32*)(Bb + slot * 1024),
                                       16, 0, 0);
    }
  };
  auto issueAtt = [&](int t) {
    p0 = *(const f32x4*)(attb + (size_t)(t * 64) * V_);
    p1 = *(const f32x4*)(attb + (size_t)(t * 64 + 1) * V_);
  };
  auto writeAtt = [&](char* Aw) {
#pragma unroll
    for (int j = 0; j < 4; ++j) {
      int v2 = vsub + j;
      half2v h;
      h[0] = (f16)p0[j]; h[1] = (f16)p1[j];
      *(half2v*)(Aw + v2 * 128 + ((4 * up) ^ (((v2 + (v2 >> 3)) & 7) << 4))) = h;
    }
  };

  // ---- prologue: stage step 0 ----
  issueAtt(0);
  stageB(0, Bb0);
  writeAtt(Ab0);
  __syncthreads();

#pragma unroll 1
  for (int t = 0; t < NSTEP; ++t) {
    char* Bc = (t & 1) ? Bb1 : Bb0;
    char* Bn = (t & 1) ? Bb0 : Bb1;
    char* Ac = (t & 1) ? Ab1 : Ab0;
    char* An = (t & 1) ? Ab0 : Ab1;
    const bool pref = (t + 1) < NSTEP;

    if (pref) {
      issueAtt(t + 1);        // att HBM loads fly across compute
      stageB(t + 1, Bn);      // glds fly across compute
    }

    KS_STEP(0, Ac, Bc, t)
    KS_STEP(1, Ac, Bc, t)

    if (pref) writeAtt(An);
    __syncthreads();
  }

  // ---- epilogue: scatter acc -> rhs[b][t][v][k*16+f] (f16)  (r7-validated) ----
#pragma unroll
  for (int ni = 0; ni < 3; ++ni) {
    int n = wn * 48 + ni * 16 + l15;
    int tt = n >> 4, fi = n & 15;
#pragma unroll
    for (int k = 0; k < 3; ++k)
#pragma unroll
      for (int vi = 0; vi < 2; ++vi)
#pragma unroll
        for (int r = 0; r < 4; ++r) {
          int v = vbase + vi * 16 + lg * 4 + r;
          rhs[((size_t)(b * T_ + tt) * V_ + v) * 48 + k * 16 + fi] =
              (f16)acc[k][vi][ni][r];
        }
  }
}

// ---------------------------------------------------------------------------
// Kernel 3: out[row, c] = relu( sum_{s=0..2} rhs[row][s*16+..] * theta[s*16+..][c] )
// ---------------------------------------------------------------------------
__global__ __launch_bounds__(256) void epi(const f16* __restrict__ rhs,
                                           const float* __restrict__ theta,
                                           float* __restrict__ out) {
  int wave = threadIdx.x >> 6, lane = threadIdx.x & 63;
  int row0 = blockIdx.x * 128 + wave * 32;
  int cl = lane & 31, kh = (lane >> 5) * 8;

  half8v bf[2][3];
#pragma unroll
  for (int nf = 0; nf < 2; ++nf)
#pragma unroll
    for (int ks = 0; ks < 3; ++ks) {
      half8v hb;
#pragma unroll
      for (int j = 0; j < 8; ++j)
        hb[j] = (f16)theta[(size_t)(ks * 16 + kh + j) * C_ + nf * 32 + cl];
      bf[nf][ks] = hb;
    }

  f32x16 acc0 = 0, acc1 = 0;
#pragma unroll
  for (int s = 0; s < 3; ++s) {
    half8v a = *(const half8v*)(rhs + (size_t)(row0 + cl) * 48 + s * 16 + kh);
    acc0 = __builtin_amdgcn_mfma_f32_32x32x16_f16(a, bf[0][s], acc0, 0, 0, 0);
    acc1 = __builtin_amdgcn_mfma_f32_32x32x16_f16(a, bf[1][s], acc1, 0, 0, 0);
  }
#pragma unroll
  for (int r = 0; r < 16; ++r) {
    int row = row0 + (r & 3) + 8 * (r >> 2) + 4 * (lane >> 5);
    out[(size_t)row * C_ + cl]      = fmaxf(acc0[r], 0.f);
    out[(size_t)row * C_ + 32 + cl] = fmaxf(acc1[r], 0.f);
  }
}

// ---------------------------------------------------------------------------
extern "C" void kernel_launch(void* const* d_in, const int* in_sizes, int n_in,
                              void* d_out, int out_size, void* d_ws, size_t ws_size,
                              hipStream_t stream) {
  const float* x     = (const float*)d_in[0];   // (8,12,2048,16)
  const float* Att   = (const float*)d_in[1];   // (8,2048,2048)
  const float* cheb  = (const float*)d_in[2];   // (3,2048,2048)
  const float* theta = (const float*)d_in[3];   // (3,16,64)
  float* out = (float*)d_out;                   // (8,12,2048,64) fp32

  const size_t xtB   = (size_t)B_ * N_ * V_ * sizeof(f16);        // 6.29 MB
  const size_t rhs1B = (size_t)B_ * T_ * V_ * 48 * sizeof(f16);   // 18.9 MB
  // chebT needs 25.2 MB after that; total 50.4 MB (ws provided ~69 MB in prior rounds)

  f16* XT  = (f16*)d_ws;
  f16* rhs = (f16*)((char*)d_ws + xtB);
  f16* cT  = (f16*)((char*)d_ws + xtB + rhs1B);

  prep_xt<<<B_ * T_ * 4, 256, 0, stream>>>(x, XT);
  prep_chebT<<<K_ * 32 * 32, 256, 0, stream>>>(cheb, cT);
  gemm6<<<B_ * 64, 256, 0, stream>>>(Att, cT, XT, rhs);
  epi<<<(B_ * T_ * V_) / 128, 256, 0, stream>>>(rhs, theta, out);
}

// Round 11
// 114.089 us; speedup vs baseline: 6.0372x; 1.0980x over previous
//
#include <hip/hip_runtime.h>
#include <hip/hip_bf16.h>
#include <stdint.h>

// cheb_conv_with_Att_static: out[b,t,v,c] = relu( sum_{k,f} theta[k,f,c] *
//     sum_u cheb[k,u,v]*Att[b,u,v]*x[b,t,u,f] )
// B=8 T=12 V=2048 F=16 K=3 C=64
#define B_  8
#define T_  12
#define V_  2048
#define F_  16
#define K_  3
#define C_  64
#define N_  192   // T*F

typedef _Float16 f16;
typedef _Float16 half2v __attribute__((ext_vector_type(2)));
typedef _Float16 half4v __attribute__((ext_vector_type(4)));
typedef _Float16 half8v __attribute__((ext_vector_type(8)));
typedef float    f32x4  __attribute__((ext_vector_type(4)));
typedef float    f32x16 __attribute__((ext_vector_type(16)));
typedef unsigned int u32;

// ---------------------------------------------------------------------------
// Kernel 1a: XT[b][n=t*16+f][u] = (f16) x[b][t][u][f]   (u becomes contiguous)
// ---------------------------------------------------------------------------
__global__ __launch_bounds__(256) void prep_xt(const float* __restrict__ x,
                                               f16* __restrict__ XT) {
  int bid = blockIdx.x;
  int bt = bid >> 2, uc = bid & 3;
  int b = bt / T_, t = bt % T_;
  __shared__ float tile[64][17];
  int r  = threadIdx.x >> 2, fq = threadIdx.x & 3;   // load mapping
  int f  = threadIdx.x >> 4, uq = threadIdx.x & 15;  // store mapping
  for (int u0 = uc * 512; u0 < uc * 512 + 512; u0 += 64) {
    f32x4 v = *(const f32x4*)(x + ((size_t)(b * T_ + t) * V_ + u0 + r) * F_ + fq * 4);
    tile[r][fq * 4 + 0] = v[0];
    tile[r][fq * 4 + 1] = v[1];
    tile[r][fq * 4 + 2] = v[2];
    tile[r][fq * 4 + 3] = v[3];
    __syncthreads();
    half4v h;
    h[0] = (f16)tile[uq * 4 + 0][f];
    h[1] = (f16)tile[uq * 4 + 1][f];
    h[2] = (f16)tile[uq * 4 + 2][f];
    h[3] = (f16)tile[uq * 4 + 3][f];
    *(half4v*)(XT + (size_t)(b * N_ + t * F_ + f) * V_ + u0 + uq * 4) = h;
    __syncthreads();
  }
}

// ---------------------------------------------------------------------------
// Kernel 1b: chebT = f16 transpose of cheb, blocked for 16x16x32 A-frags:
//   elem(k,v,u) at (((k*128 + (v>>4))*256 + (u>>3))*16 + (v&15))*8 + (u&7)
// (validated in rounds 7/10)
// ---------------------------------------------------------------------------
__global__ __launch_bounds__(256) void prep_chebT(const float* __restrict__ c,
                                                  f16* __restrict__ cT) {
  int bid = blockIdx.x;
  int vt = bid & 31, ut = (bid >> 5) & 31, k = bid >> 10;
  int u0 = ut * 64, v0 = vt * 64;
  __shared__ float tile[64][68];
  int tid = threadIdx.x;
  int lr = tid >> 4, lc = (tid & 15) * 4;
  const float* src = c + ((size_t)k * V_ + u0) * V_ + v0;
#pragma unroll
  for (int i = 0; i < 4; ++i) {
    f32x4 v = *(const f32x4*)(src + (size_t)(lr + 16 * i) * V_ + lc);
    tile[lr + 16 * i][lc + 0] = v[0];
    tile[lr + 16 * i][lc + 1] = v[1];
    tile[lr + 16 * i][lc + 2] = v[2];
    tile[lr + 16 * i][lc + 3] = v[3];
  }
  __syncthreads();
  int vl = tid & 63, uc0 = tid >> 6;
#pragma unroll
  for (int i = 0; i < 2; ++i) {
    int uc = uc0 + 4 * i;                 // u-chunk 0..7
    half8v h;
#pragma unroll
    for (int j = 0; j < 8; ++j) h[j] = (f16)tile[uc * 8 + j][vl];
    int vb16 = vt * 4 + (vl >> 4);        // v>>4
    int vi   = vl & 15;
    int ub8  = ut * 8 + uc;               // u>>3
    size_t off = ((((size_t)k * 128 + vb16) * 256 + ub8) * 16 + vi) * 8;
    *(half8v*)(cT + off) = h;
  }
}

// ---------------------------------------------------------------------------
// Kernel 2 (round-11): r10 structure + HALF-STEP cheb register pipeline.
// Per (b,vt): all 3 k, full K=2048:
//   rhs[b][t][v][k*16+f] = sum_u (cheb[k,u,v]*Att[b,u,v]) * XT[b,n,u]
// BM=32, BN=192, BK=64; 4 waves (1v x 4n), wave tile 32v x 48n, 16x16x32 MFMA.
// acc = 72 AGPR; cheb dbuf cfX/cfY = 48 VGPR; total ~212 <= 256 (LB(256,2))
// -> 2 waves/SIMD from 2 INDEPENDENT blocks (LDS 56KB -> 2 blocks/CU).
// cfY(t,KS1) issued at step top (covered by KS0); cfX(t+1,KS0) issued between
// KS0 and KS1 (covered by KS1 + barrier) -> no at-use L3 latency on cheb.
// att read once (HBM floor), B via glds dbuf, all addressing validated in r10.
// ---------------------------------------------------------------------------
#define MFMA16(a, b, c) __builtin_amdgcn_mfma_f32_16x16x32_f16(a, b, c, 0, 0, 0)

#define KS_STEP(ks, AC, BC, CF)                                                 \
  {                                                                             \
    const int ub = (ks) * 64 + lg * 16;                                         \
    half8v af0 = *(const half8v*)((AC) + l15 * 128 + (ub ^ ak0));               \
    half8v af1 = *(const half8v*)((AC) + (l15 + 16) * 128 + (ub ^ ak1));        \
    half8v b0 = *(const half8v*)((BC) + n0 * 128 + (ub ^ bk0));                 \
    half8v b1 = *(const half8v*)((BC) + n1 * 128 + (ub ^ bk1));                 \
    half8v b2 = *(const half8v*)((BC) + n2 * 128 + (ub ^ bk2));                 \
    half8v a00 = CF[0] * af0, a01 = CF[1] * af1;                                \
    half8v a10 = CF[2] * af0, a11 = CF[3] * af1;                                \
    half8v a20 = CF[4] * af0, a21 = CF[5] * af1;                                \
    __builtin_amdgcn_s_setprio(1);                                              \
    acc[0][0][0] = MFMA16(a00, b0, acc[0][0][0]);                               \
    acc[0][0][1] = MFMA16(a00, b1, acc[0][0][1]);                               \
    acc[0][0][2] = MFMA16(a00, b2, acc[0][0][2]);                               \
    acc[0][1][0] = MFMA16(a01, b0, acc[0][1][0]);                               \
    acc[0][1][1] = MFMA16(a01, b1, acc[0][1][1]);                               \
    acc[0][1][2] = MFMA16(a01, b2, acc[0][1][2]);                               \
    acc[1][0][0] = MFMA16(a10, b0, acc[1][0][0]);                               \
    acc[1][0][1] = MFMA16(a10, b1, acc[1][0][1]);                               \
    acc[1][0][2] = MFMA16(a10, b2, acc[1][0][2]);                               \
    acc[1][1][0] = MFMA16(a11, b0, acc[1][1][0]);                               \
    acc[1][1][1] = MFMA16(a11, b1, acc[1][1][1]);                               \
    acc[1][1][2] = MFMA16(a11, b2, acc[1][1][2]);                               \
    acc[2][0][0] = MFMA16(a20, b0, acc[2][0][0]);                               \
    acc[2][0][1] = MFMA16(a20, b1, acc[2][0][1]);                               \
    acc[2][0][2] = MFMA16(a20, b2, acc[2][0][2]);                               \
    acc[2][1][0] = MFMA16(a21, b0, acc[2][1][0]);                               \
    acc[2][1][1] = MFMA16(a21, b1, acc[2][1][1]);                               \
    acc[2][1][2] = MFMA16(a21, b2, acc[2][1][2]);                               \
    __builtin_amdgcn_s_setprio(0);                                              \
  }

__global__ __launch_bounds__(256, 2) void gemm7(const float* __restrict__ Att,
                                                const f16* __restrict__ chebT,
                                                const f16* __restrict__ XT,
                                                f16* __restrict__ rhs) {
  constexpr int NSTEP = V_ / 64;          // 32
  const int bid = blockIdx.x;
  const int vt = bid & 63;                // vt%8 == bid%8 -> XCD-pinned cheb
  const int b  = bid >> 6;
  const int vbase = vt * 32;

  __shared__ char smem[57344];            // B0 24K | B1 24K | A0 4K | A1 4K
  char* Bb0 = smem;
  char* Bb1 = smem + 24576;
  char* Ab0 = smem + 49152;
  char* Ab1 = smem + 53248;

  const int tid = threadIdx.x;
  const int wave = tid >> 6, lane = tid & 63;
  const int wn = wave;                    // 1v x 4n wave grid
  const int l15 = lane & 15, lg = lane >> 4;

  // A (att) swizzle keys for the two 16-row v-frags (rows l15, l15+16)
  const int va0 = l15, va1 = l15 + 16;
  const int ak0 = ((va0 + (va0 >> 3)) & 7) << 4;
  const int ak1 = ((va1 + (va1 >> 3)) & 7) << 4;

  // B fragments: 3 n-subtiles per wave
  const int n0 = wn * 48 + l15, n1 = n0 + 16, n2 = n0 + 32;
  const int bk0 = (n0 & 7) << 4, bk1 = (n1 & 7) << 4, bk2 = (n2 & 7) << 4;

  // cheb lane base pointers (k x vi), 16-blocked layout (validated r7/r10)
  const f16* chb00 = chebT + ((size_t)(vt * 2 + 0) * 256) * 128 + lg * 128 + l15 * 8;
  const f16* chb01 = chebT + ((size_t)(vt * 2 + 1) * 256) * 128 + lg * 128 + l15 * 8;
  const f16* chb10 = chb00 + (size_t)V_ * V_;
  const f16* chb11 = chb01 + (size_t)V_ * V_;
  const f16* chb20 = chb10 + (size_t)V_ * V_;
  const f16* chb21 = chb11 + (size_t)V_ * V_;

  // att staging: thread covers 4v x 2u  (vsub = (tid&7)*4, up = tid>>3)
  const int vsub = (tid & 7) * 4;
  const int up   = tid >> 3;              // 0..31 -> u pair {2up, 2up+1}
  const float* attb = Att + (size_t)b * V_ * V_ + (size_t)(2 * up) * V_ + vbase + vsub;

  // B glds: 24 slots x 1KB, 6 per wave (validated r6/r8/r10)
  const f16* xtb = XT + (size_t)b * N_ * V_;

  f32x4 acc[3][2][3];
#pragma unroll
  for (int k = 0; k < 3; ++k)
#pragma unroll
    for (int vi = 0; vi < 2; ++vi)
#pragma unroll
      for (int ni = 0; ni < 3; ++ni) acc[k][vi][ni] = 0;

  f32x4 p0, p1;
  half8v cfX[6], cfY[6];

  auto stageB = [&](int t, char* Bb) {
#pragma unroll
    for (int e = 0; e < 6; ++e) {
      int slot = wave * 6 + e;
      int n = slot * 8 + (lane >> 3);
      int cc = (lane & 7) ^ (n & 7);
      const f16* src = xtb + (size_t)n * V_ + t * 64 + cc * 8;
      __builtin_amdgcn_global_load_lds((const __attribute__((address_space(1))) u32*)src,
                                       (__attribute__((address_space(3))) u32*)(Bb + slot * 1024),
                                       16, 0, 0);
    }
  };
  auto issueAtt = [&](int t) {
    p0 = *(const f32x4*)(attb + (size_t)(t * 64) * V_);
    p1 = *(const f32x4*)(attb + (size_t)(t * 64 + 1) * V_);
  };
  auto writeAtt = [&](char* Aw) {
#pragma unroll
    for (int j = 0; j < 4; ++j) {
      int v2 = vsub + j;
      half2v h;
      h[0] = (f16)p0[j]; h[1] = (f16)p1[j];
      *(half2v*)(Aw + v2 * 128 + ((4 * up) ^ (((v2 + (v2 >> 3)) & 7) << 4))) = h;
    }
  };
  // half-step cheb frag load: 6 frags (3k x 2vi) = 24 VGPR
  auto loadChebHalf = [&](int t, int ks, half8v cf[6]) {
    const size_t co = (size_t)(t * 8 + ks * 4) * 128;
    cf[0] = *(const half8v*)(chb00 + co);
    cf[1] = *(const half8v*)(chb01 + co);
    cf[2] = *(const half8v*)(chb10 + co);
    cf[3] = *(const half8v*)(chb11 + co);
    cf[4] = *(const half8v*)(chb20 + co);
    cf[5] = *(const half8v*)(chb21 + co);
  };

  // ---- prologue: stage step 0 + first half-step cheb ----
  issueAtt(0);
  stageB(0, Bb0);
  loadChebHalf(0, 0, cfX);
  writeAtt(Ab0);
  __syncthreads();

#pragma unroll 1
  for (int t = 0; t < NSTEP; ++t) {
    char* Bc = (t & 1) ? Bb1 : Bb0;
    char* Bn = (t & 1) ? Bb0 : Bb1;
    char* Ac = (t & 1) ? Ab1 : Ab0;
    char* An = (t & 1) ? Ab0 : Ab1;
    const bool pref = (t + 1) < NSTEP;

    loadChebHalf(t, 1, cfY);    // for KS1 below: covered by KS0 compute
    if (pref) {
      issueAtt(t + 1);          // att HBM loads fly across compute
      stageB(t + 1, Bn);        // glds fly across compute
    }

    KS_STEP(0, Ac, Bc, cfX)

    if (pref) loadChebHalf(t + 1, 0, cfX);   // covered by KS1 + barrier

    KS_STEP(1, Ac, Bc, cfY)

    if (pref) writeAtt(An);
    __syncthreads();
  }

  // ---- epilogue: scatter acc -> rhs[b][t][v][k*16+f] (f16)  (r10-validated) ----
#pragma unroll
  for (int ni = 0; ni < 3; ++ni) {
    int n = wn * 48 + ni * 16 + l15;
    int tt = n >> 4, fi = n & 15;
#pragma unroll
    for (int k = 0; k < 3; ++k)
#pragma unroll
      for (int vi = 0; vi < 2; ++vi)
#pragma unroll
        for (int r = 0; r < 4; ++r) {
          int v = vbase + vi * 16 + lg * 4 + r;
          rhs[((size_t)(b * T_ + tt) * V_ + v) * 48 + k * 16 + fi] =
              (f16)acc[k][vi][ni][r];
        }
  }
}

// ---------------------------------------------------------------------------
// Kernel 3: out[row, c] = relu( sum_{s=0..2} rhs[row][s*16+..] * theta[s*16+..][c] )
// ---------------------------------------------------------------------------
__global__ __launch_bounds__(256) void epi(const f16* __restrict__ rhs,
                                           const float* __restrict__ theta,
                                           float* __restrict__ out) {
  int wave = threadIdx.x >> 6, lane = threadIdx.x & 63;
  int row0 = blockIdx.x * 128 + wave * 32;
  int cl = lane & 31, kh = (lane >> 5) * 8;

  half8v bf[2][3];
#pragma unroll
  for (int nf = 0; nf < 2; ++nf)
#pragma unroll
    for (int ks = 0; ks < 3; ++ks) {
      half8v hb;
#pragma unroll
      for (int j = 0; j < 8; ++j)
        hb[j] = (f16)theta[(size_t)(ks * 16 + kh + j) * C_ + nf * 32 + cl];
      bf[nf][ks] = hb;
    }

  f32x16 acc0 = 0, acc1 = 0;
#pragma unroll
  for (int s = 0; s < 3; ++s) {
    half8v a = *(const half8v*)(rhs + (size_t)(row0 + cl) * 48 + s * 16 + kh);
    acc0 = __builtin_amdgcn_mfma_f32_32x32x16_f16(a, bf[0][s], acc0, 0, 0, 0);
    acc1 = __builtin_amdgcn_mfma_f32_32x32x16_f16(a, bf[1][s], acc1, 0, 0, 0);
  }
#pragma unroll
  for (int r = 0; r < 16; ++r) {
    int row = row0 + (r & 3) + 8 * (r >> 2) + 4 * (lane >> 5);
    out[(size_t)row * C_ + cl]      = fmaxf(acc0[r], 0.f);
    out[(size_t)row * C_ + 32 + cl] = fmaxf(acc1[r], 0.f);
  }
}

// ---------------------------------------------------------------------------
extern "C" void kernel_launch(void* const* d_in, const int* in_sizes, int n_in,
                              void* d_out, int out_size, void* d_ws, size_t ws_size,
                              hipStream_t stream) {
  const float* x     = (const float*)d_in[0];   // (8,12,2048,16)
  const float* Att   = (const float*)d_in[1];   // (8,2048,2048)
  const float* cheb  = (const float*)d_in[2];   // (3,2048,2048)
  const float* theta = (const float*)d_in[3];   // (3,16,64)
  float* out = (float*)d_out;                   // (8,12,2048,64) fp32

  const size_t xtB   = (size_t)B_ * N_ * V_ * sizeof(f16);        // 6.29 MB
  const size_t rhs1B = (size_t)B_ * T_ * V_ * 48 * sizeof(f16);   // 18.9 MB

  f16* XT  = (f16*)d_ws;
  f16* rhs = (f16*)((char*)d_ws + xtB);
  f16* cT  = (f16*)((char*)d_ws + xtB + rhs1B);

  prep_xt<<<B_ * T_ * 4, 256, 0, stream>>>(x, XT);
  prep_chebT<<<K_ * 32 * 32, 256, 0, stream>>>(cheb, cT);
  gemm7<<<B_ * 64, 256, 0, stream>>>(Att, cT, XT, rhs);
  epi<<<(B_ * T_ * V_) / 128, 256, 0, stream>>>(rhs, theta, out);
}